// Round 7
// baseline (374.710 us; speedup 1.0000x reference)
//
#include <hip/hip_runtime.h>
#include <stdint.h>

typedef __bf16 bf16x8 __attribute__((ext_vector_type(8)));
typedef float f32x4 __attribute__((ext_vector_type(4)));
typedef unsigned short ushort_t;

#define N_OUT 11008
#define K_DIM 4096
#define M_DIM 512
#define BM 256
#define BN 64
#define BK 64
#define KHALF 2048
#define NT 32 /* KHALF / BK */

__constant__ float c_nf4[16] = {
    -1.0f, -0.6961928009986877f, -0.5250730514526367f, -0.39491748809814453f,
    -0.28444138169288635f, -0.18477343022823334f, -0.09105003625154495f, 0.0f,
    0.07958029955625534f, 0.16093020141124725f, 0.24611230194568634f,
    0.33791524171829224f, 0.44070982933044434f, 0.5626170039176941f,
    0.7229568362236023f, 1.0f};

// round-half-up fp32 -> bf16, pack two into u32
__device__ __forceinline__ uint32_t pkbf(float lo, float hi) {
  uint32_t ul = __builtin_bit_cast(uint32_t, lo);
  uint32_t uh = __builtin_bit_cast(uint32_t, hi);
  return ((ul + 0x8000u) >> 16) | ((uh + 0x8000u) & 0xffff0000u);
}

__device__ __forceinline__ void async16(const void* g, void* l) {
  __builtin_amdgcn_global_load_lds(
      (const __attribute__((address_space(1))) void*)g,
      (__attribute__((address_space(3))) void*)l, 16, 0, 0);
}

__device__ __forceinline__ bf16x8 ldfrag(const ushort_t* p) {
  uint4 r = *reinterpret_cast<const uint4*>(p);
  return __builtin_bit_cast(bf16x8, r);
}

// byte (= two packed nibbles) -> two scaled bf16 via pair LUT
__device__ __forceinline__ uint32_t dqb(uint32_t byte, float s, const float2* lut) {
  float2 l = lut[byte];
  return pkbf(l.x * s, l.y * s);
}

// ====== fused prep: idx nibble-pack | cvt+swizzle | x@A | B^T ================
// grid: [0,11008) pack, [11008,12032) cvt, [12032,12544) xa, [12544,12587) bt
// (bias-init: out zeroed by hipMemsetAsync; bias folds into k_main acc init)
__global__ void k_prep(const float* __restrict__ x, const int* __restrict__ wi,
                       const float* __restrict__ lA, const float* __restrict__ lB,
                       ushort_t* __restrict__ xbf, ushort_t* __restrict__ xap,
                       ushort_t* __restrict__ btp, uint8_t* __restrict__ wpk) {
  const int b = blockIdx.x, t = threadIdx.x;
  if (b < 11008) {
    // nibble-pack weight indices: int32 -> 4-bit, 8x smaller (180 -> 22.5 MB).
    // byte j of the output qword = idx[2j] | idx[2j+1]<<4  (pair-LUT index!)
    // thread handles 16 consecutive k of one row: 64 B in, 8 B out, coalesced.
    int g = b * 256 + t;  // uint2 id, 2,818,048 total
    int o = g >> 8;       // row (4096/16 = 256 chunks per row)
    int kc = g & 255;
    const int4* src = (const int4*)(wi + (size_t)o * K_DIM + kc * 16);
    int4 a0 = src[0], a1 = src[1], a2 = src[2], a3 = src[3];
    uint32_t lo = (uint32_t)a0.x | ((uint32_t)a0.y << 4) | ((uint32_t)a0.z << 8) |
                  ((uint32_t)a0.w << 12) | ((uint32_t)a1.x << 16) |
                  ((uint32_t)a1.y << 20) | ((uint32_t)a1.z << 24) |
                  ((uint32_t)a1.w << 28);
    uint32_t hi = (uint32_t)a2.x | ((uint32_t)a2.y << 4) | ((uint32_t)a2.z << 8) |
                  ((uint32_t)a2.w << 12) | ((uint32_t)a3.x << 16) |
                  ((uint32_t)a3.y << 20) | ((uint32_t)a3.z << 24) |
                  ((uint32_t)a3.w << 28);
    ((uint2*)wpk)[g] = make_uint2(lo, hi);
  } else if (b < 12032) {
    // x fp32 -> bf16 with XOR chunk swizzle inside each 64-elem k-window:
    // stored chunk position cp holds original chunk cp ^ (m&7)
    int oc = (b - 11008) * 256 + t;  // 16B output chunk id (8 bf16)
    int m = oc >> 9;                 // 512 chunks per row
    int cr = oc & 511;
    int win = cr >> 3, cp = cr & 7;
    int c = cp ^ (m & 7);
    const float4* s4 = (const float4*)(x + (size_t)m * K_DIM + win * 64 + c * 8);
    float4 v0 = s4[0], v1 = s4[1];
    uint4 o;
    o.x = pkbf(v0.x, v0.y);
    o.y = pkbf(v0.z, v0.w);
    o.z = pkbf(v1.x, v1.y);
    o.w = pkbf(v1.z, v1.w);
    ((uint4*)xbf)[oc] = o;
  } else if (b < 12544) {
    // xa = 2*(x @ lora_A) for one row m, padded [512,32] bf16.
    // COALESCED: thread t handles k = i*256 + t.
    __shared__ float red[256 * 17];
    int m = b - 12032;
    f32x4 ac0 = 0.f, ac1 = 0.f, ac2 = 0.f, ac3 = 0.f;
#pragma unroll
    for (int i = 0; i < 16; ++i) {
      int k = i * 256 + t;
      float xk = x[(size_t)m * K_DIM + k];
      const f32x4* l4 = (const f32x4*)(lA + (size_t)k * 16);
      ac0 += xk * l4[0];
      ac1 += xk * l4[1];
      ac2 += xk * l4[2];
      ac3 += xk * l4[3];
    }
#pragma unroll
    for (int r = 0; r < 4; ++r) {
      red[t * 17 + r] = ac0[r];
      red[t * 17 + 4 + r] = ac1[r];
      red[t * 17 + 8 + r] = ac2[r];
      red[t * 17 + 12 + r] = ac3[r];
    }
    __syncthreads();
#pragma unroll
    for (int s = 128; s >= 16; s >>= 1) {
      if (t < s)
        for (int r = 0; r < 16; ++r) red[t * 17 + r] += red[(t + s) * 17 + r];
      __syncthreads();
    }
    if (t < 32) {
      float v = 0.f;
      if (t < 16) {
        for (int p = 0; p < 16; ++p) v += red[p * 17 + t];
        v *= 2.0f;  // SCALING
      }
      uint32_t u = __builtin_bit_cast(uint32_t, v);
      xap[(size_t)m * 32 + t] = (ushort_t)((u + 0x8000u) >> 16);
    }
  } else {
    // Bt = lora_B^T, padded [11008,32] bf16
    int o = (b - 12544) * 256 + t;
    uint32_t p[8];
#pragma unroll
    for (int j = 0; j < 8; ++j)
      p[j] = pkbf(lB[(size_t)(2 * j) * N_OUT + o], lB[(size_t)(2 * j + 1) * N_OUT + o]);
    uint4* dst = reinterpret_cast<uint4*>(btp + (size_t)o * 32);
    dst[0] = make_uint4(p[0], p[1], p[2], p[3]);
    dst[1] = make_uint4(p[4], p[5], p[6], p[7]);
    dst[2] = make_uint4(0u, 0u, 0u, 0u);
    dst[3] = make_uint4(0u, 0u, 0u, 0u);
  }
}

// =============== main fused GEMM (split-K=2, atomic epilogue) ===============
// EXACT R0/R6 loop structure (unbeaten): two __syncthreads per tile,
// compiler-scheduled. Change this round: indices come nibble-packed from wpk
// (22.5 MB, L2/L3-resident) -> per-tile idx prefetch is ONE 8-byte dwordx2
// with ~L2/L3 latency that fits inside the MFMA-phase window, instead of
// 64 B of int32 idx from HBM (~900 cy) that never landed in time.
// BM=256 x BN=64, BK=64, 4 waves; wave w owns rows [w*64, w*64+64), acc 4x4.
__launch_bounds__(256, 3)
__global__ void k_main(const ushort_t* __restrict__ xbf, const uint8_t* __restrict__ wpk,
                       const float* __restrict__ sc, const ushort_t* __restrict__ xap,
                       const ushort_t* __restrict__ btp,
                       const float* __restrict__ bias, float* __restrict__ out) {
  __shared__ __align__(16) ushort_t lds_a[BM * BK];  // 32 KB, [row][c'], swizzled
  __shared__ __align__(16) ushort_t lds_b[BN * 72];  // 9 KB, +8 pad
  __shared__ float2 lutp[256];                       // pair LUT, 2 KB

  const int t = threadIdx.x;
  const int lane = t & 63;
  const int w = t >> 6;
  const int o0 = blockIdx.x * BN;
  const int m0 = blockIdx.y * BM;
  const int kh = blockIdx.z;
  const int k0 = kh * KHALF;

  lutp[t] = make_float2(c_nf4[t & 15], c_nf4[t >> 4]);

  // B staging: thread -> (row=t>>2, 16 idx = 8 packed bytes at (t&3)*16)
  const int brow = t >> 2, bq = t & 3;
  const uint2* gpb =
      (const uint2*)(wpk + (size_t)(o0 + brow) * (K_DIM / 2) + (k0 >> 1) + bq * 8);
  const float* gs = sc + (size_t)(o0 + brow) * 64 + kh * 32;  // 1 scale/row/tile
  ushort_t* lb = lds_b + brow * 72 + bq * 16;

  // A DMA: wave w stages its own rows [w*64, w*64+64); 8 instrs x 1KB
  const ushort_t* ga =
      xbf + (size_t)(m0 + w * 64 + (lane >> 3)) * K_DIM + k0 + (lane & 7) * 8;
  ushort_t* la_dst = lds_a + w * 4096 + lane * 8;

  // acc init: kh==1 carries the bias (out itself is zero-filled by memset)
  const int cl = lane & 15;
  f32x4 acc[4][4];
#pragma unroll
  for (int ni = 0; ni < 4; ++ni) {
    float b0 = (kh == 1) ? bias[o0 + ni * 16 + cl] : 0.f;
#pragma unroll
    for (int mi = 0; mi < 4; ++mi) acc[mi][ni] = (f32x4){b0, b0, b0, b0};
  }

  // prologue: prefetch tile 0 packed idx + scale
  uint2 bp = gpb[0];
  float s = gs[0];
  uint4 braw;

  const ushort_t* afb = lds_a + (w * 64 + (lane & 15)) * BK;
  const int q = lane >> 4;
  const ushort_t* bfb = lds_b + (lane & 15) * 72 + q * 8;

#pragma unroll 1
  for (int kt = 0; kt < NT; ++kt) {
    __syncthreads();  // prev tile's frag reads done (covers LUT init at kt=0)
    // dequant 16 idx (8 packed bytes) -> 16 bf16 via pair LUT, 2x ds_write_b128
    {
      uint32_t lo = bp.x, hi = bp.y;
      uint4 w0, w1;
      w0.x = dqb(lo & 255u, s, lutp);
      w0.y = dqb((lo >> 8) & 255u, s, lutp);
      w0.z = dqb((lo >> 16) & 255u, s, lutp);
      w0.w = dqb(lo >> 24, s, lutp);
      w1.x = dqb(hi & 255u, s, lutp);
      w1.y = dqb((hi >> 8) & 255u, s, lutp);
      w1.z = dqb((hi >> 16) & 255u, s, lutp);
      w1.w = dqb(hi >> 24, s, lutp);
      *reinterpret_cast<uint4*>(lb) = w0;
      *reinterpret_cast<uint4*>(lb + 8) = w1;
    }
    // A DMA for this tile (own wave's rows only)
#pragma unroll
    for (int j = 0; j < 8; ++j)
      async16(ga + (size_t)j * 8 * K_DIM + kt * BK, la_dst + j * 512);
    __syncthreads();  // drains DMA + makes lds_b visible
    // prefetch next tile (in flight during MFMA phase; L2/L3-resident now)
    if (kt + 1 < NT) {
      bp = gpb[(kt + 1) * 4];
      s = gs[kt + 1];
    } else if (kh == 1) {
      braw = *reinterpret_cast<const uint4*>(btp + (size_t)(o0 + brow) * 32 + bq * 8);
    }
    // fragments + 32 MFMA
#pragma unroll
    for (int kc = 0; kc < 2; ++kc) {
      const int cpr = ((kc * 4 + q) ^ (lane & 7)) * 8;  // un-swizzle
      bf16x8 av[4], bv[4];
#pragma unroll
      for (int mi = 0; mi < 4; ++mi) av[mi] = ldfrag(afb + mi * 16 * BK + cpr);
#pragma unroll
      for (int ni = 0; ni < 4; ++ni) bv[ni] = ldfrag(bfb + ni * 16 * 72 + kc * 32);
#pragma unroll
      for (int mi = 0; mi < 4; ++mi)
#pragma unroll
        for (int ni = 0; ni < 4; ++ni)
          acc[mi][ni] = __builtin_amdgcn_mfma_f32_16x16x32_bf16(av[mi], bv[ni],
                                                                acc[mi][ni], 0, 0, 0);
    }
  }

  // LoRA K-extension tail (kh==1 only): BK=32, A from xap, B from btp
  if (kh == 1) {
    __syncthreads();
    *reinterpret_cast<uint4*>(lds_b + brow * 72 + bq * 8) = braw;
#pragma unroll
    for (int j = 0; j < 4; ++j)
      async16(xap + (size_t)(m0 + w * 64 + j * 16 + (lane >> 2)) * 32 + (lane & 3) * 8,
              lds_a + w * 2048 + j * 512 + lane * 8);
    __syncthreads();
    bf16x8 av[4], bv[4];
#pragma unroll
    for (int mi = 0; mi < 4; ++mi)
      av[mi] = ldfrag(lds_a + w * 2048 + (mi * 16 + (lane & 15)) * 32 + q * 8);
#pragma unroll
    for (int ni = 0; ni < 4; ++ni)
      bv[ni] = ldfrag(lds_b + (ni * 16 + (lane & 15)) * 72 + q * 8);
#pragma unroll
    for (int mi = 0; mi < 4; ++mi)
#pragma unroll
      for (int ni = 0; ni < 4; ++ni)
        acc[mi][ni] = __builtin_amdgcn_mfma_f32_16x16x32_bf16(av[mi], bv[ni],
                                                              acc[mi][ni], 0, 0, 0);
  }

  // epilogue: atomic add onto zero-initialized out
  const int rg = q * 4;
#pragma unroll
  for (int ni = 0; ni < 4; ++ni) {
    int col = o0 + ni * 16 + cl;
#pragma unroll
    for (int mi = 0; mi < 4; ++mi) {
      int row0 = m0 + w * 64 + mi * 16 + rg;
      float* op = out + (size_t)row0 * N_OUT + col;
#pragma unroll
      for (int i = 0; i < 4; ++i) atomicAdd(op + (size_t)i * N_OUT, acc[mi][ni][i]);
    }
  }
}

extern "C" void kernel_launch(void* const* d_in, const int* in_sizes, int n_in,
                              void* d_out, int out_size, void* d_ws, size_t ws_size,
                              hipStream_t stream) {
  const float* x = (const float*)d_in[0];
  const int* wi = (const int*)d_in[1];
  const float* sc = (const float*)d_in[2];
  const float* lA = (const float*)d_in[3];
  const float* lB = (const float*)d_in[4];
  const float* bias = (const float*)d_in[5];
  float* out = (float*)d_out;

  char* wsb = (char*)d_ws;
  ushort_t* xbf = (ushort_t*)wsb;                               // 4 MB
  ushort_t* xap = (ushort_t*)(wsb + (4u << 20));                // 32 KB
  ushort_t* btp = (ushort_t*)(wsb + (4u << 20) + (32u << 10));  // 704 KB
  uint8_t* wpk = (uint8_t*)(wsb + (5u << 20));                  // 22.5 MB packed idx

  hipMemsetAsync(out, 0, (size_t)out_size, stream);  // replaces bias-broadcast
  k_prep<<<12587, 256, 0, stream>>>(x, wi, lA, lB, xbf, xap, btp, wpk);
  dim3 grid(N_OUT / BN, M_DIM / BM, 2);
  k_main<<<grid, 256, 0, stream>>>(xbf, wpk, sc, xap, btp, bias, out);
}

// Round 9
// 372.566 us; speedup vs baseline: 1.0058x; 1.0058x over previous
//
#include <hip/hip_runtime.h>
#include <stdint.h>

typedef __bf16 bf16x8 __attribute__((ext_vector_type(8)));
typedef float f32x4 __attribute__((ext_vector_type(4)));
typedef unsigned short ushort_t;

#define N_OUT 11008
#define K_DIM 4096
#define M_DIM 512
#define BM 256
#define BN 64
#define BK 64
#define KHALF 2048
#define NT 32 /* KHALF / BK */
#define BSTRIDE (BN * 72)

__constant__ float c_nf4[16] = {
    -1.0f, -0.6961928009986877f, -0.5250730514526367f, -0.39491748809814453f,
    -0.28444138169288635f, -0.18477343022823334f, -0.09105003625154495f, 0.0f,
    0.07958029955625534f, 0.16093020141124725f, 0.24611230194568634f,
    0.33791524171829224f, 0.44070982933044434f, 0.5626170039176941f,
    0.7229568362236023f, 1.0f};

// round-half-up fp32 -> bf16, pack two into u32
__device__ __forceinline__ uint32_t pkbf(float lo, float hi) {
  uint32_t ul = __builtin_bit_cast(uint32_t, lo);
  uint32_t uh = __builtin_bit_cast(uint32_t, hi);
  return ((ul + 0x8000u) >> 16) | ((uh + 0x8000u) & 0xffff0000u);
}

__device__ __forceinline__ void async16(const void* g, void* l) {
  __builtin_amdgcn_global_load_lds(
      (const __attribute__((address_space(1))) void*)g,
      (__attribute__((address_space(3))) void*)l, 16, 0, 0);
}

__device__ __forceinline__ bf16x8 ldfrag(const ushort_t* p) {
  uint4 r = *reinterpret_cast<const uint4*>(p);
  return __builtin_bit_cast(bf16x8, r);
}

// byte (= two packed nibbles) -> two scaled bf16 via pair LUT
__device__ __forceinline__ uint32_t dqb(uint32_t byte, float s, const float2* lut) {
  float2 l = lut[byte];
  return pkbf(l.x * s, l.y * s);
}

// ====== fused prep: idx nibble-pack | cvt+swizzle | x@A | B^T ================
// grid: [0,11008) pack, [11008,12032) cvt, [12032,12544) xa, [12544,12587) bt
// (bias-init: out zeroed by hipMemsetAsync; bias folds into k_main acc init)
__global__ void k_prep(const float* __restrict__ x, const int* __restrict__ wi,
                       const float* __restrict__ lA, const float* __restrict__ lB,
                       ushort_t* __restrict__ xbf, ushort_t* __restrict__ xap,
                       ushort_t* __restrict__ btp, uint8_t* __restrict__ wpk) {
  const int b = blockIdx.x, t = threadIdx.x;
  if (b < 11008) {
    // nibble-pack row b of wi: int32 -> 4-bit (180 -> 22.5 MB), COALESCED:
    // thread t loads int4 #(j*256+t) (lane-contiguous 4 KB/instr), packs 4 idx
    // into a u16, exchanges via LDS, stores 8 B/thread contiguous.
    __shared__ uint16_t pk[1024];
    const int4* src = (const int4*)(wi + (size_t)b * K_DIM);
#pragma unroll
    for (int j = 0; j < 4; ++j) {
      int4 a = src[j * 256 + t];
      pk[j * 256 + t] = (uint16_t)((uint32_t)a.x | ((uint32_t)a.y << 4) |
                                   ((uint32_t)a.z << 8) | ((uint32_t)a.w << 12));
    }
    __syncthreads();
    ((uint2*)(wpk + (size_t)b * (K_DIM / 2)))[t] =
        *reinterpret_cast<const uint2*>(&pk[4 * t]);
  } else if (b < 12032) {
    // x fp32 -> bf16 with XOR chunk swizzle inside each 64-elem k-window:
    // stored chunk position cp holds original chunk cp ^ (m&7)
    int oc = (b - 11008) * 256 + t;  // 16B output chunk id (8 bf16)
    int m = oc >> 9;                 // 512 chunks per row
    int cr = oc & 511;
    int win = cr >> 3, cp = cr & 7;
    int c = cp ^ (m & 7);
    const float4* s4 = (const float4*)(x + (size_t)m * K_DIM + win * 64 + c * 8);
    float4 v0 = s4[0], v1 = s4[1];
    uint4 o;
    o.x = pkbf(v0.x, v0.y);
    o.y = pkbf(v0.z, v0.w);
    o.z = pkbf(v1.x, v1.y);
    o.w = pkbf(v1.z, v1.w);
    ((uint4*)xbf)[oc] = o;
  } else if (b < 12544) {
    // xa = 2*(x @ lora_A) for one row m, padded [512,32] bf16.
    // COALESCED: thread t handles k = i*256 + t.
    __shared__ float red[256 * 17];
    int m = b - 12032;
    f32x4 ac0 = 0.f, ac1 = 0.f, ac2 = 0.f, ac3 = 0.f;
#pragma unroll
    for (int i = 0; i < 16; ++i) {
      int k = i * 256 + t;
      float xk = x[(size_t)m * K_DIM + k];
      const f32x4* l4 = (const f32x4*)(lA + (size_t)k * 16);
      ac0 += xk * l4[0];
      ac1 += xk * l4[1];
      ac2 += xk * l4[2];
      ac3 += xk * l4[3];
    }
#pragma unroll
    for (int r = 0; r < 4; ++r) {
      red[t * 17 + r] = ac0[r];
      red[t * 17 + 4 + r] = ac1[r];
      red[t * 17 + 8 + r] = ac2[r];
      red[t * 17 + 12 + r] = ac3[r];
    }
    __syncthreads();
#pragma unroll
    for (int s = 128; s >= 16; s >>= 1) {
      if (t < s)
        for (int r = 0; r < 16; ++r) red[t * 17 + r] += red[(t + s) * 17 + r];
      __syncthreads();
    }
    if (t < 32) {
      float v = 0.f;
      if (t < 16) {
        for (int p = 0; p < 16; ++p) v += red[p * 17 + t];
        v *= 2.0f;  // SCALING
      }
      uint32_t u = __builtin_bit_cast(uint32_t, v);
      xap[(size_t)m * 32 + t] = (ushort_t)((u + 0x8000u) >> 16);
    }
  } else {
    // Bt = lora_B^T, padded [11008,32] bf16
    int o = (b - 12544) * 256 + t;
    uint32_t p[8];
#pragma unroll
    for (int j = 0; j < 8; ++j)
      p[j] = pkbf(lB[(size_t)(2 * j) * N_OUT + o], lB[(size_t)(2 * j + 1) * N_OUT + o]);
    uint4* dst = reinterpret_cast<uint4*>(btp + (size_t)o * 32);
    dst[0] = make_uint4(p[0], p[1], p[2], p[3]);
    dst[1] = make_uint4(p[4], p[5], p[6], p[7]);
    dst[2] = make_uint4(0u, 0u, 0u, 0u);
    dst[3] = make_uint4(0u, 0u, 0u, 0u);
  }
}

// =============== main fused GEMM (split-K=2, atomic epilogue) ===============
// R7 loop with sync1 REMOVED: packed idx live in registers, so the only
// consumer of sync1 was lds_b reuse -> double-buffer lds_b (LDS 53.2 KB,
// still 3 blocks/CU) and run ONE __syncthreads per tile:
//   dequant(kt)->b[kt&1] | A-DMA(kt) | sync (drains DMA, publishes b) |
//   bp prefetch (L2-resident wpk, lands during MFMA) | frags + 32 MFMA.
// Safety: lds_a rows are wave-private (own reads retire before own next DMA);
// b[kt&1] is only read post-sync(kt), written pre-sync(kt); b[(kt-1)&1]
// readers and b[kt&1] writers touch different buffers.
__launch_bounds__(256, 3)
__global__ void k_main(const ushort_t* __restrict__ xbf, const uint8_t* __restrict__ wpk,
                       const float* __restrict__ sc, const ushort_t* __restrict__ xap,
                       const ushort_t* __restrict__ btp,
                       const float* __restrict__ bias, float* __restrict__ out) {
  __shared__ __align__(16) ushort_t lds_a[BM * BK];     // 32 KB, [row][c'], swizzled
  __shared__ __align__(16) ushort_t lds_b[2][BSTRIDE];  // 2 x 9 KB, +8 pad, dbuf
  __shared__ float2 lutp[256];                          // pair LUT, 2 KB

  const int t = threadIdx.x;
  const int lane = t & 63;
  const int w = t >> 6;
  const int o0 = blockIdx.x * BN;
  const int m0 = blockIdx.y * BM;
  const int kh = blockIdx.z;
  const int k0 = kh * KHALF;

  lutp[t] = make_float2(c_nf4[t & 15], c_nf4[t >> 4]);

  // B staging: thread -> (row=t>>2, 16 idx = 8 packed bytes at (t&3)*16)
  const int brow = t >> 2, bq = t & 3;
  const uint2* gpb =
      (const uint2*)(wpk + (size_t)(o0 + brow) * (K_DIM / 2) + (k0 >> 1) + bq * 8);
  const float* gs = sc + (size_t)(o0 + brow) * 64 + kh * 32;  // 1 scale/row/tile
  ushort_t* lb = &lds_b[0][brow * 72 + bq * 16];

  // A DMA: wave w stages its own rows [w*64, w*64+64); 8 instrs x 1KB
  const ushort_t* ga =
      xbf + (size_t)(m0 + w * 64 + (lane >> 3)) * K_DIM + k0 + (lane & 7) * 8;
  ushort_t* la_dst = lds_a + w * 4096 + lane * 8;

  // acc init: kh==1 carries the bias (out itself is zero-filled by memset)
  const int cl = lane & 15;
  f32x4 acc[4][4];
#pragma unroll
  for (int ni = 0; ni < 4; ++ni) {
    float b0 = (kh == 1) ? bias[o0 + ni * 16 + cl] : 0.f;
#pragma unroll
    for (int mi = 0; mi < 4; ++mi) acc[mi][ni] = (f32x4){b0, b0, b0, b0};
  }

  // prologue: prefetch tile 0 packed idx + scale
  uint2 bp = gpb[0];
  float s = gs[0];
  uint4 braw;

  const ushort_t* afb = lds_a + (w * 64 + (lane & 15)) * BK;
  const int q = lane >> 4;
  const ushort_t* bfb = &lds_b[0][(lane & 15) * 72 + q * 8];

  __syncthreads();  // lutp visible before first dequant

#pragma unroll 1
  for (int kt = 0; kt < NT; ++kt) {
    // dequant 16 idx (8 packed bytes) -> 16 bf16 via pair LUT into b[kt&1]
    {
      uint32_t lo = bp.x, hi = bp.y;
      uint4 w0, w1;
      w0.x = dqb(lo & 255u, s, lutp);
      w0.y = dqb((lo >> 8) & 255u, s, lutp);
      w0.z = dqb((lo >> 16) & 255u, s, lutp);
      w0.w = dqb(lo >> 24, s, lutp);
      w1.x = dqb(hi & 255u, s, lutp);
      w1.y = dqb((hi >> 8) & 255u, s, lutp);
      w1.z = dqb((hi >> 16) & 255u, s, lutp);
      w1.w = dqb(hi >> 24, s, lutp);
      ushort_t* lbk = lb + (kt & 1) * BSTRIDE;
      *reinterpret_cast<uint4*>(lbk) = w0;
      *reinterpret_cast<uint4*>(lbk + 8) = w1;
    }
    // A DMA for this tile (own wave's rows only)
#pragma unroll
    for (int j = 0; j < 8; ++j)
      async16(ga + (size_t)j * 8 * K_DIM + kt * BK, la_dst + j * 512);
    __syncthreads();  // drains DMA + publishes b[kt&1]
    // prefetch next tile's packed idx (L2-resident, lands during MFMA phase)
    if (kt + 1 < NT) {
      bp = gpb[(kt + 1) * 4];
      s = gs[kt + 1];
    } else if (kh == 1) {
      braw = *reinterpret_cast<const uint4*>(btp + (size_t)(o0 + brow) * 32 + bq * 8);
    }
    // fragments + 32 MFMA
    const ushort_t* bfbk = bfb + (kt & 1) * BSTRIDE;
#pragma unroll
    for (int kc = 0; kc < 2; ++kc) {
      const int cpr = ((kc * 4 + q) ^ (lane & 7)) * 8;  // un-swizzle
      bf16x8 av[4], bv[4];
#pragma unroll
      for (int mi = 0; mi < 4; ++mi) av[mi] = ldfrag(afb + mi * 16 * BK + cpr);
#pragma unroll
      for (int ni = 0; ni < 4; ++ni) bv[ni] = ldfrag(bfbk + ni * 16 * 72 + kc * 32);
#pragma unroll
      for (int mi = 0; mi < 4; ++mi)
#pragma unroll
        for (int ni = 0; ni < 4; ++ni)
          acc[mi][ni] = __builtin_amdgcn_mfma_f32_16x16x32_bf16(av[mi], bv[ni],
                                                                acc[mi][ni], 0, 0, 0);
    }
  }

  // LoRA K-extension tail (kh==1 only): BK=32, A from xap, B from btp
  if (kh == 1) {
    __syncthreads();
    *reinterpret_cast<uint4*>(&lds_b[0][brow * 72 + bq * 8]) = braw;
#pragma unroll
    for (int j = 0; j < 4; ++j)
      async16(xap + (size_t)(m0 + w * 64 + j * 16 + (lane >> 2)) * 32 + (lane & 3) * 8,
              lds_a + w * 2048 + j * 512 + lane * 8);
    __syncthreads();
    bf16x8 av[4], bv[4];
#pragma unroll
    for (int mi = 0; mi < 4; ++mi)
      av[mi] = ldfrag(lds_a + w * 2048 + (mi * 16 + (lane & 15)) * 32 + q * 8);
#pragma unroll
    for (int ni = 0; ni < 4; ++ni)
      bv[ni] = ldfrag(&lds_b[0][(ni * 16 + (lane & 15)) * 72 + q * 8]);
#pragma unroll
    for (int mi = 0; mi < 4; ++mi)
#pragma unroll
      for (int ni = 0; ni < 4; ++ni)
        acc[mi][ni] = __builtin_amdgcn_mfma_f32_16x16x32_bf16(av[mi], bv[ni],
                                                              acc[mi][ni], 0, 0, 0);
  }

  // epilogue: atomic add onto zero-initialized out
  const int rg = q * 4;
#pragma unroll
  for (int ni = 0; ni < 4; ++ni) {
    int col = o0 + ni * 16 + cl;
#pragma unroll
    for (int mi = 0; mi < 4; ++mi) {
      int row0 = m0 + w * 64 + mi * 16 + rg;
      float* op = out + (size_t)row0 * N_OUT + col;
#pragma unroll
      for (int i = 0; i < 4; ++i) atomicAdd(op + (size_t)i * N_OUT, acc[mi][ni][i]);
    }
  }
}

extern "C" void kernel_launch(void* const* d_in, const int* in_sizes, int n_in,
                              void* d_out, int out_size, void* d_ws, size_t ws_size,
                              hipStream_t stream) {
  const float* x = (const float*)d_in[0];
  const int* wi = (const int*)d_in[1];
  const float* sc = (const float*)d_in[2];
  const float* lA = (const float*)d_in[3];
  const float* lB = (const float*)d_in[4];
  const float* bias = (const float*)d_in[5];
  float* out = (float*)d_out;

  char* wsb = (char*)d_ws;
  ushort_t* xbf = (ushort_t*)wsb;                               // 4 MB
  ushort_t* xap = (ushort_t*)(wsb + (4u << 20));                // 32 KB
  ushort_t* btp = (ushort_t*)(wsb + (4u << 20) + (32u << 10));  // 704 KB
  uint8_t* wpk = (uint8_t*)(wsb + (5u << 20));                  // 22.5 MB packed idx

  hipMemsetAsync(out, 0, (size_t)out_size, stream);  // replaces bias-broadcast
  k_prep<<<12587, 256, 0, stream>>>(x, wi, lA, lB, xbf, xap, btp, wpk);
  dim3 grid(N_OUT / BN, M_DIM / BM, 2);
  k_main<<<grid, 256, 0, stream>>>(xbf, wpk, sc, xap, btp, bias, out);
}

// Round 11
// 367.417 us; speedup vs baseline: 1.0198x; 1.0140x over previous
//
#include <hip/hip_runtime.h>
#include <stdint.h>

typedef __bf16 bf16x8 __attribute__((ext_vector_type(8)));
typedef float f32x4 __attribute__((ext_vector_type(4)));
typedef unsigned short ushort_t;

#define N_OUT 11008
#define K_DIM 4096
#define M_DIM 512
#define BM 256
#define BN 64
#define BK 64
#define KHALF 2048
#define NT 32 /* KHALF / BK */
#define BSTRIDE (BN * 72)

__constant__ float c_nf4[16] = {
    -1.0f, -0.6961928009986877f, -0.5250730514526367f, -0.39491748809814453f,
    -0.28444138169288635f, -0.18477343022823334f, -0.09105003625154495f, 0.0f,
    0.07958029955625534f, 0.16093020141124725f, 0.24611230194568634f,
    0.33791524171829224f, 0.44070982933044434f, 0.5626170039176941f,
    0.7229568362236023f, 1.0f};

// round-half-up fp32 -> bf16, pack two into u32
__device__ __forceinline__ uint32_t pkbf(float lo, float hi) {
  uint32_t ul = __builtin_bit_cast(uint32_t, lo);
  uint32_t uh = __builtin_bit_cast(uint32_t, hi);
  return ((ul + 0x8000u) >> 16) | ((uh + 0x8000u) & 0xffff0000u);
}

__device__ __forceinline__ void async16(const void* g, void* l) {
  __builtin_amdgcn_global_load_lds(
      (const __attribute__((address_space(1))) void*)g,
      (__attribute__((address_space(3))) void*)l, 16, 0, 0);
}

__device__ __forceinline__ bf16x8 ldfrag(const ushort_t* p) {
  uint4 r = *reinterpret_cast<const uint4*>(p);
  return __builtin_bit_cast(bf16x8, r);
}

// byte (= two packed nibbles) -> two scaled bf16 via pair LUT
__device__ __forceinline__ uint32_t dqb(uint32_t byte, float s, const float2* lut) {
  float2 l = lut[byte];
  return pkbf(l.x * s, l.y * s);
}

__device__ __forceinline__ uint32_t nib8(int4 a, int4 b) {
  return (uint32_t)a.x | ((uint32_t)a.y << 4) | ((uint32_t)a.z << 8) |
         ((uint32_t)a.w << 12) | ((uint32_t)b.x << 16) | ((uint32_t)b.y << 20) |
         ((uint32_t)b.z << 24) | ((uint32_t)b.w << 28);
}

// ====== fused prep: idx nibble-pack | cvt+swizzle | x@A | B^T ================
// FAT-BLOCK grid, 2187 blocks total (was 12587 — per-block dispatch overhead
// ~3 ns/block was costing ~35 us):
//   [0,1376) pack 8 rows/block, [1376,1632) cvt x4, [1632,2144) xa, [2144,2187) bt
// (bias-init: out zeroed by hipMemsetAsync; bias folds into k_main acc init)
__global__ void k_prep(const float* __restrict__ x, const int* __restrict__ wi,
                       const float* __restrict__ lA, const float* __restrict__ lB,
                       ushort_t* __restrict__ xbf, ushort_t* __restrict__ xap,
                       ushort_t* __restrict__ btp, uint8_t* __restrict__ wpk) {
  const int b = blockIdx.x, t = threadIdx.x;
  if (b < 1376) {
    // nibble-pack 8 rows of wi: int32 -> 4-bit (180 -> 22.5 MB).
    // thread t handles k [16t,16t+16) of each row: 64 B contiguous read,
    // 8 B contiguous write; no LDS, no syncs.
    // ROW STRIDES: src = 1024 int4/row (4096 int32), dst = 256 uint2/row.
    // (R10 bug: src stride was 256 -> wrong weights; fixed to 1024.)
    const int4* src = (const int4*)(wi + (size_t)b * 8 * K_DIM);
    uint2* dst = (uint2*)(wpk + (size_t)b * 8 * (K_DIM / 2));
#pragma unroll
    for (int rr = 0; rr < 8; ++rr) {
      const int4* s4 = src + rr * 1024 + t * 4;  // 1024 int4 per row
      int4 a0 = s4[0], a1 = s4[1], a2 = s4[2], a3 = s4[3];
      dst[rr * 256 + t] = make_uint2(nib8(a0, a1), nib8(a2, a3));
    }
  } else if (b < 1632) {
    // x fp32 -> bf16 with XOR chunk swizzle inside each 64-elem k-window:
    // stored chunk position cp holds original chunk cp ^ (m&7). 4 chunks/thread.
    int base = (b - 1376) * 1024 + t;
#pragma unroll
    for (int i = 0; i < 4; ++i) {
      int oc = base + i * 256;  // 16B output chunk id (8 bf16)
      int m = oc >> 9;          // 512 chunks per row
      int cr = oc & 511;
      int win = cr >> 3, cp = cr & 7;
      int c = cp ^ (m & 7);
      const float4* s4 = (const float4*)(x + (size_t)m * K_DIM + win * 64 + c * 8);
      float4 v0 = s4[0], v1 = s4[1];
      uint4 o;
      o.x = pkbf(v0.x, v0.y);
      o.y = pkbf(v0.z, v0.w);
      o.z = pkbf(v1.x, v1.y);
      o.w = pkbf(v1.z, v1.w);
      ((uint4*)xbf)[oc] = o;
    }
  } else if (b < 2144) {
    // xa = 2*(x @ lora_A) for one row m, padded [512,32] bf16.
    // COALESCED: thread t handles k = i*256 + t.
    __shared__ float red[256 * 17];
    int m = b - 1632;
    f32x4 ac0 = 0.f, ac1 = 0.f, ac2 = 0.f, ac3 = 0.f;
#pragma unroll
    for (int i = 0; i < 16; ++i) {
      int k = i * 256 + t;
      float xk = x[(size_t)m * K_DIM + k];
      const f32x4* l4 = (const f32x4*)(lA + (size_t)k * 16);
      ac0 += xk * l4[0];
      ac1 += xk * l4[1];
      ac2 += xk * l4[2];
      ac3 += xk * l4[3];
    }
#pragma unroll
    for (int r = 0; r < 4; ++r) {
      red[t * 17 + r] = ac0[r];
      red[t * 17 + 4 + r] = ac1[r];
      red[t * 17 + 8 + r] = ac2[r];
      red[t * 17 + 12 + r] = ac3[r];
    }
    __syncthreads();
#pragma unroll
    for (int s = 128; s >= 16; s >>= 1) {
      if (t < s)
        for (int r = 0; r < 16; ++r) red[t * 17 + r] += red[(t + s) * 17 + r];
      __syncthreads();
    }
    if (t < 32) {
      float v = 0.f;
      if (t < 16) {
        for (int p = 0; p < 16; ++p) v += red[p * 17 + t];
        v *= 2.0f;  // SCALING
      }
      uint32_t u = __builtin_bit_cast(uint32_t, v);
      xap[(size_t)m * 32 + t] = (ushort_t)((u + 0x8000u) >> 16);
    }
  } else {
    // Bt = lora_B^T, padded [11008,32] bf16
    int o = (b - 2144) * 256 + t;
    uint32_t p[8];
#pragma unroll
    for (int j = 0; j < 8; ++j)
      p[j] = pkbf(lB[(size_t)(2 * j) * N_OUT + o], lB[(size_t)(2 * j + 1) * N_OUT + o]);
    uint4* dst = reinterpret_cast<uint4*>(btp + (size_t)o * 32);
    dst[0] = make_uint4(p[0], p[1], p[2], p[3]);
    dst[1] = make_uint4(p[4], p[5], p[6], p[7]);
    dst[2] = make_uint4(0u, 0u, 0u, 0u);
    dst[3] = make_uint4(0u, 0u, 0u, 0u);
  }
}

// =============== main fused GEMM (split-K=2, atomic epilogue) ===============
// UNCHANGED from R9 (verified correct, <=106 us): single __syncthreads per
// tile, lds_b double-buffered, packed idx in registers (wpk L2-resident).
__launch_bounds__(256, 3)
__global__ void k_main(const ushort_t* __restrict__ xbf, const uint8_t* __restrict__ wpk,
                       const float* __restrict__ sc, const ushort_t* __restrict__ xap,
                       const ushort_t* __restrict__ btp,
                       const float* __restrict__ bias, float* __restrict__ out) {
  __shared__ __align__(16) ushort_t lds_a[BM * BK];     // 32 KB, [row][c'], swizzled
  __shared__ __align__(16) ushort_t lds_b[2][BSTRIDE];  // 2 x 9 KB, +8 pad, dbuf
  __shared__ float2 lutp[256];                          // pair LUT, 2 KB

  const int t = threadIdx.x;
  const int lane = t & 63;
  const int w = t >> 6;
  const int o0 = blockIdx.x * BN;
  const int m0 = blockIdx.y * BM;
  const int kh = blockIdx.z;
  const int k0 = kh * KHALF;

  lutp[t] = make_float2(c_nf4[t & 15], c_nf4[t >> 4]);

  // B staging: thread -> (row=t>>2, 16 idx = 8 packed bytes at (t&3)*16)
  const int brow = t >> 2, bq = t & 3;
  const uint2* gpb =
      (const uint2*)(wpk + (size_t)(o0 + brow) * (K_DIM / 2) + (k0 >> 1) + bq * 8);
  const float* gs = sc + (size_t)(o0 + brow) * 64 + kh * 32;  // 1 scale/row/tile
  ushort_t* lb = &lds_b[0][brow * 72 + bq * 16];

  // A DMA: wave w stages its own rows [w*64, w*64+64); 8 instrs x 1KB
  const ushort_t* ga =
      xbf + (size_t)(m0 + w * 64 + (lane >> 3)) * K_DIM + k0 + (lane & 7) * 8;
  ushort_t* la_dst = lds_a + w * 4096 + lane * 8;

  // acc init: kh==1 carries the bias (out itself is zero-filled by memset)
  const int cl = lane & 15;
  f32x4 acc[4][4];
#pragma unroll
  for (int ni = 0; ni < 4; ++ni) {
    float b0 = (kh == 1) ? bias[o0 + ni * 16 + cl] : 0.f;
#pragma unroll
    for (int mi = 0; mi < 4; ++mi) acc[mi][ni] = (f32x4){b0, b0, b0, b0};
  }

  // prologue: prefetch tile 0 packed idx + scale
  uint2 bp = gpb[0];
  float s = gs[0];
  uint4 braw;

  const ushort_t* afb = lds_a + (w * 64 + (lane & 15)) * BK;
  const int q = lane >> 4;
  const ushort_t* bfb = &lds_b[0][(lane & 15) * 72 + q * 8];

  __syncthreads();  // lutp visible before first dequant

#pragma unroll 1
  for (int kt = 0; kt < NT; ++kt) {
    // dequant 16 idx (8 packed bytes) -> 16 bf16 via pair LUT into b[kt&1]
    {
      uint32_t lo = bp.x, hi = bp.y;
      uint4 w0, w1;
      w0.x = dqb(lo & 255u, s, lutp);
      w0.y = dqb((lo >> 8) & 255u, s, lutp);
      w0.z = dqb((lo >> 16) & 255u, s, lutp);
      w0.w = dqb(lo >> 24, s, lutp);
      w1.x = dqb(hi & 255u, s, lutp);
      w1.y = dqb((hi >> 8) & 255u, s, lutp);
      w1.z = dqb((hi >> 16) & 255u, s, lutp);
      w1.w = dqb(hi >> 24, s, lutp);
      ushort_t* lbk = lb + (kt & 1) * BSTRIDE;
      *reinterpret_cast<uint4*>(lbk) = w0;
      *reinterpret_cast<uint4*>(lbk + 8) = w1;
    }
    // A DMA for this tile (own wave's rows only)
#pragma unroll
    for (int j = 0; j < 8; ++j)
      async16(ga + (size_t)j * 8 * K_DIM + kt * BK, la_dst + j * 512);
    __syncthreads();  // drains DMA + publishes b[kt&1]
    // prefetch next tile's packed idx (L2-resident, lands during MFMA phase)
    if (kt + 1 < NT) {
      bp = gpb[(kt + 1) * 4];
      s = gs[kt + 1];
    } else if (kh == 1) {
      braw = *reinterpret_cast<const uint4*>(btp + (size_t)(o0 + brow) * 32 + bq * 8);
    }
    // fragments + 32 MFMA
    const ushort_t* bfbk = bfb + (kt & 1) * BSTRIDE;
#pragma unroll
    for (int kc = 0; kc < 2; ++kc) {
      const int cpr = ((kc * 4 + q) ^ (lane & 7)) * 8;  // un-swizzle
      bf16x8 av[4], bv[4];
#pragma unroll
      for (int mi = 0; mi < 4; ++mi) av[mi] = ldfrag(afb + mi * 16 * BK + cpr);
#pragma unroll
      for (int ni = 0; ni < 4; ++ni) bv[ni] = ldfrag(bfbk + ni * 16 * 72 + kc * 32);
#pragma unroll
      for (int mi = 0; mi < 4; ++mi)
#pragma unroll
        for (int ni = 0; ni < 4; ++ni)
          acc[mi][ni] = __builtin_amdgcn_mfma_f32_16x16x32_bf16(av[mi], bv[ni],
                                                                acc[mi][ni], 0, 0, 0);
    }
  }

  // LoRA K-extension tail (kh==1 only): BK=32, A from xap, B from btp
  if (kh == 1) {
    __syncthreads();
    *reinterpret_cast<uint4*>(&lds_b[0][brow * 72 + bq * 8]) = braw;
#pragma unroll
    for (int j = 0; j < 4; ++j)
      async16(xap + (size_t)(m0 + w * 64 + j * 16 + (lane >> 2)) * 32 + (lane & 3) * 8,
              lds_a + w * 2048 + j * 512 + lane * 8);
    __syncthreads();
    bf16x8 av[4], bv[4];
#pragma unroll
    for (int mi = 0; mi < 4; ++mi)
      av[mi] = ldfrag(lds_a + w * 2048 + (mi * 16 + (lane & 15)) * 32 + q * 8);
#pragma unroll
    for (int ni = 0; ni < 4; ++ni)
      bv[ni] = ldfrag(&lds_b[0][(ni * 16 + (lane & 15)) * 72 + q * 8]);
#pragma unroll
    for (int mi = 0; mi < 4; ++mi)
#pragma unroll
      for (int ni = 0; ni < 4; ++ni)
        acc[mi][ni] = __builtin_amdgcn_mfma_f32_16x16x32_bf16(av[mi], bv[ni],
                                                              acc[mi][ni], 0, 0, 0);
  }

  // epilogue: atomic add onto zero-initialized out
  const int rg = q * 4;
#pragma unroll
  for (int ni = 0; ni < 4; ++ni) {
    int col = o0 + ni * 16 + cl;
#pragma unroll
    for (int mi = 0; mi < 4; ++mi) {
      int row0 = m0 + w * 64 + mi * 16 + rg;
      float* op = out + (size_t)row0 * N_OUT + col;
#pragma unroll
      for (int i = 0; i < 4; ++i) atomicAdd(op + (size_t)i * N_OUT, acc[mi][ni][i]);
    }
  }
}

extern "C" void kernel_launch(void* const* d_in, const int* in_sizes, int n_in,
                              void* d_out, int out_size, void* d_ws, size_t ws_size,
                              hipStream_t stream) {
  const float* x = (const float*)d_in[0];
  const int* wi = (const int*)d_in[1];
  const float* sc = (const float*)d_in[2];
  const float* lA = (const float*)d_in[3];
  const float* lB = (const float*)d_in[4];
  const float* bias = (const float*)d_in[5];
  float* out = (float*)d_out;

  char* wsb = (char*)d_ws;
  ushort_t* xbf = (ushort_t*)wsb;                               // 4 MB
  ushort_t* xap = (ushort_t*)(wsb + (4u << 20));                // 32 KB
  ushort_t* btp = (ushort_t*)(wsb + (4u << 20) + (32u << 10));  // 704 KB
  uint8_t* wpk = (uint8_t*)(wsb + (5u << 20));                  // 22.5 MB packed idx

  hipMemsetAsync(out, 0, (size_t)out_size, stream);  // replaces bias-broadcast
  k_prep<<<2187, 256, 0, stream>>>(x, wi, lA, lB, xbf, xap, btp, wpk);
  dim3 grid(N_OUT / BN, M_DIM / BM, 2);
  k_main<<<grid, 256, 0, stream>>>(xbf, wpk, sc, xap, btp, bias, out);
}

// Round 12
// 341.442 us; speedup vs baseline: 1.0974x; 1.0761x over previous
//
#include <hip/hip_runtime.h>
#include <stdint.h>

typedef __bf16 bf16x8 __attribute__((ext_vector_type(8)));
typedef float f32x4 __attribute__((ext_vector_type(4)));
typedef unsigned short ushort_t;

#define N_OUT 11008
#define K_DIM 4096
#define M_DIM 512
#define BM 256
#define BN 64
#define BK 64
#define KHALF 2048
#define NT 32 /* KHALF / BK */
#define BSTRIDE (BN * 72)

__constant__ float c_nf4[16] = {
    -1.0f, -0.6961928009986877f, -0.5250730514526367f, -0.39491748809814453f,
    -0.28444138169288635f, -0.18477343022823334f, -0.09105003625154495f, 0.0f,
    0.07958029955625534f, 0.16093020141124725f, 0.24611230194568634f,
    0.33791524171829224f, 0.44070982933044434f, 0.5626170039176941f,
    0.7229568362236023f, 1.0f};

// round-half-up fp32 -> bf16, pack two into u32
__device__ __forceinline__ uint32_t pkbf(float lo, float hi) {
  uint32_t ul = __builtin_bit_cast(uint32_t, lo);
  uint32_t uh = __builtin_bit_cast(uint32_t, hi);
  return ((ul + 0x8000u) >> 16) | ((uh + 0x8000u) & 0xffff0000u);
}

__device__ __forceinline__ void async16(const void* g, void* l) {
  __builtin_amdgcn_global_load_lds(
      (const __attribute__((address_space(1))) void*)g,
      (__attribute__((address_space(3))) void*)l, 16, 0, 0);
}

__device__ __forceinline__ bf16x8 ldfrag(const ushort_t* p) {
  uint4 r = *reinterpret_cast<const uint4*>(p);
  return __builtin_bit_cast(bf16x8, r);
}

__device__ __forceinline__ uint32_t dq2(int a, int b, float s, const float2* lut) {
  float2 l = lut[a | (b << 4)];
  return pkbf(l.x * s, l.y * s);
}

// ====== fused prep: cvt+swizzle | x@A | B^T (811 fat blocks, no pack) ========
// grid: [0,256) cvt x4, [256,768) xa, [768,811) bt
// (bias-init: out zeroed by hipMemsetAsync; bias folds into k_main acc init)
__global__ void k_prep(const float* __restrict__ x, const float* __restrict__ lA,
                       const float* __restrict__ lB,
                       ushort_t* __restrict__ xbf, ushort_t* __restrict__ xap,
                       ushort_t* __restrict__ btp) {
  const int b = blockIdx.x, t = threadIdx.x;
  if (b < 256) {
    // x fp32 -> bf16 with XOR chunk swizzle inside each 64-elem k-window:
    // stored chunk position cp holds original chunk cp ^ (m&7). 4 chunks/thread.
    int base = b * 1024 + t;
#pragma unroll
    for (int i = 0; i < 4; ++i) {
      int oc = base + i * 256;  // 16B output chunk id (8 bf16)
      int m = oc >> 9;          // 512 chunks per row
      int cr = oc & 511;
      int win = cr >> 3, cp = cr & 7;
      int c = cp ^ (m & 7);
      const float4* s4 = (const float4*)(x + (size_t)m * K_DIM + win * 64 + c * 8);
      float4 v0 = s4[0], v1 = s4[1];
      uint4 o;
      o.x = pkbf(v0.x, v0.y);
      o.y = pkbf(v0.z, v0.w);
      o.z = pkbf(v1.x, v1.y);
      o.w = pkbf(v1.z, v1.w);
      ((uint4*)xbf)[oc] = o;
    }
  } else if (b < 768) {
    // xa = 2*(x @ lora_A) for one row m, padded [512,32] bf16.
    // COALESCED: thread t handles k = i*256 + t.
    __shared__ float red[256 * 17];
    int m = b - 256;
    f32x4 ac0 = 0.f, ac1 = 0.f, ac2 = 0.f, ac3 = 0.f;
#pragma unroll
    for (int i = 0; i < 16; ++i) {
      int k = i * 256 + t;
      float xk = x[(size_t)m * K_DIM + k];
      const f32x4* l4 = (const f32x4*)(lA + (size_t)k * 16);
      ac0 += xk * l4[0];
      ac1 += xk * l4[1];
      ac2 += xk * l4[2];
      ac3 += xk * l4[3];
    }
#pragma unroll
    for (int r = 0; r < 4; ++r) {
      red[t * 17 + r] = ac0[r];
      red[t * 17 + 4 + r] = ac1[r];
      red[t * 17 + 8 + r] = ac2[r];
      red[t * 17 + 12 + r] = ac3[r];
    }
    __syncthreads();
#pragma unroll
    for (int s = 128; s >= 16; s >>= 1) {
      if (t < s)
        for (int r = 0; r < 16; ++r) red[t * 17 + r] += red[(t + s) * 17 + r];
      __syncthreads();
    }
    if (t < 32) {
      float v = 0.f;
      if (t < 16) {
        for (int p = 0; p < 16; ++p) v += red[p * 17 + t];
        v *= 2.0f;  // SCALING
      }
      uint32_t u = __builtin_bit_cast(uint32_t, v);
      xap[(size_t)m * 32 + t] = (ushort_t)((u + 0x8000u) >> 16);
    }
  } else {
    // Bt = lora_B^T, padded [11008,32] bf16
    int o = (b - 768) * 256 + t;
    uint32_t p[8];
#pragma unroll
    for (int j = 0; j < 8; ++j)
      p[j] = pkbf(lB[(size_t)(2 * j) * N_OUT + o], lB[(size_t)(2 * j + 1) * N_OUT + o]);
    uint4* dst = reinterpret_cast<uint4*>(btp + (size_t)o * 32);
    dst[0] = make_uint4(p[0], p[1], p[2], p[3]);
    dst[1] = make_uint4(p[4], p[5], p[6], p[7]);
    dst[2] = make_uint4(0u, 0u, 0u, 0u);
    dst[3] = make_uint4(0u, 0u, 0u, 0u);
  }
}

// =============== main fused GEMM (split-K=2, atomic epilogue) ===============
// RE-FUSED: direct wi reads (no pack kernel — R6's data path, which beat the
// unfused wpk architecture by 20 us overall) + the two k_main-local wins
// proven on the wpk line:
//   1. SINGLE __syncthreads per tile (R9/R11 structure, passed): lds_b double-
//      buffered, idx lives in registers, barrier only drains DMA + publishes b.
//   2. XCD-chunked bijective swizzle (R1: FETCH -36%): the 4 siblings
//      (2 m-blocks x 2 kh) sharing one wi panel run adjacently on one XCD ->
//      later siblings' idx loads hit L2 (~300cy) instead of HBM (~900cy),
//      attacking the one stall scheduling never fixed.
// BM=256 x BN=64, BK=64, 4 waves; wave w owns rows [w*64, w*64+64), acc 4x4.
__launch_bounds__(256, 3)
__global__ void k_main(const ushort_t* __restrict__ xbf, const int* __restrict__ wi,
                       const float* __restrict__ sc, const ushort_t* __restrict__ xap,
                       const ushort_t* __restrict__ btp,
                       const float* __restrict__ bias, float* __restrict__ out) {
  __shared__ __align__(16) ushort_t lds_a[BM * BK];     // 32 KB, [row][c'], swizzled
  __shared__ __align__(16) ushort_t lds_b[2][BSTRIDE];  // 2 x 9 KB, +8 pad, dbuf
  __shared__ float2 lutp[256];                          // pair LUT, 2 KB

  const int t = threadIdx.x;
  const int lane = t & 63;
  const int w = t >> 6;

  // XCD swizzle: 688 = 8 XCDs x 86 (bijective). Consecutive wg on one XCD
  // walk the 4 (m0,kh) siblings of each o-panel, then the next o-panel.
  const int n = blockIdx.x;
  const int wg = (n & 7) * 86 + (n >> 3);
  const int o0 = (wg >> 2) * BN;
  const int kh = (wg >> 1) & 1;
  const int m0 = (wg & 1) * BM;
  const int k0 = kh * KHALF;

  lutp[t] = make_float2(c_nf4[t & 15], c_nf4[t >> 4]);

  // B staging: thread -> (row=t>>2, 16 ints at (t&3)*16)
  const int brow = t >> 2, bq = t & 3;
  const int* gb = wi + (size_t)(o0 + brow) * K_DIM + k0 + bq * 16;
  const float* gs = sc + (size_t)(o0 + brow) * 64 + kh * 32;  // 1 scale/row/tile
  ushort_t* lb = &lds_b[0][brow * 72 + bq * 16];

  // A DMA: wave w stages its own rows [w*64, w*64+64); 8 instrs x 1KB
  const ushort_t* ga =
      xbf + (size_t)(m0 + w * 64 + (lane >> 3)) * K_DIM + k0 + (lane & 7) * 8;
  ushort_t* la_dst = lds_a + w * 4096 + lane * 8;

  // acc init: kh==1 carries the bias (out itself is zero-filled by memset)
  const int cl = lane & 15;
  f32x4 acc[4][4];
#pragma unroll
  for (int ni = 0; ni < 4; ++ni) {
    float b0 = (kh == 1) ? bias[o0 + ni * 16 + cl] : 0.f;
#pragma unroll
    for (int mi = 0; mi < 4; ++mi) acc[mi][ni] = (f32x4){b0, b0, b0, b0};
  }

  // prologue: prefetch tile 0 indices + scale
  int4 bi0 = ((const int4*)gb)[0], bi1 = ((const int4*)gb)[1];
  int4 bi2 = ((const int4*)gb)[2], bi3 = ((const int4*)gb)[3];
  float s = gs[0];
  gb += BK;
  uint4 braw;

  const ushort_t* afb = lds_a + (w * 64 + (lane & 15)) * BK;
  const int q = lane >> 4;
  const ushort_t* bfb = &lds_b[0][(lane & 15) * 72 + q * 8];

  __syncthreads();  // lutp visible before first dequant

#pragma unroll 1
  for (int kt = 0; kt < NT; ++kt) {
    // dequant 16 idx -> 16 bf16 via pair LUT into b[kt&1]
    {
      uint4 w0, w1;
      w0.x = dq2(bi0.x, bi0.y, s, lutp);
      w0.y = dq2(bi0.z, bi0.w, s, lutp);
      w0.z = dq2(bi1.x, bi1.y, s, lutp);
      w0.w = dq2(bi1.z, bi1.w, s, lutp);
      w1.x = dq2(bi2.x, bi2.y, s, lutp);
      w1.y = dq2(bi2.z, bi2.w, s, lutp);
      w1.z = dq2(bi3.x, bi3.y, s, lutp);
      w1.w = dq2(bi3.z, bi3.w, s, lutp);
      ushort_t* lbk = lb + (kt & 1) * BSTRIDE;
      *reinterpret_cast<uint4*>(lbk) = w0;
      *reinterpret_cast<uint4*>(lbk + 8) = w1;
    }
    // A DMA for this tile (own wave's rows only)
#pragma unroll
    for (int j = 0; j < 8; ++j)
      async16(ga + (size_t)j * 8 * K_DIM + kt * BK, la_dst + j * 512);
    __syncthreads();  // drains DMA + publishes b[kt&1]
    // prefetch next tile's indices (in flight across the MFMA phase; consumed
    // at next-iter dequant BEFORE any barrier -> no forced drain)
    if (kt + 1 < NT) {
      bi0 = ((const int4*)gb)[0];
      bi1 = ((const int4*)gb)[1];
      bi2 = ((const int4*)gb)[2];
      bi3 = ((const int4*)gb)[3];
      s = gs[kt + 1];
      gb += BK;
    } else if (kh == 1) {
      braw = *reinterpret_cast<const uint4*>(btp + (size_t)(o0 + brow) * 32 + bq * 8);
    }
    // fragments + 32 MFMA
    const ushort_t* bfbk = bfb + (kt & 1) * BSTRIDE;
#pragma unroll
    for (int kc = 0; kc < 2; ++kc) {
      const int cpr = ((kc * 4 + q) ^ (lane & 7)) * 8;  // un-swizzle
      bf16x8 av[4], bv[4];
#pragma unroll
      for (int mi = 0; mi < 4; ++mi) av[mi] = ldfrag(afb + mi * 16 * BK + cpr);
#pragma unroll
      for (int ni = 0; ni < 4; ++ni) bv[ni] = ldfrag(bfbk + ni * 16 * 72 + kc * 32);
#pragma unroll
      for (int mi = 0; mi < 4; ++mi)
#pragma unroll
        for (int ni = 0; ni < 4; ++ni)
          acc[mi][ni] = __builtin_amdgcn_mfma_f32_16x16x32_bf16(av[mi], bv[ni],
                                                                acc[mi][ni], 0, 0, 0);
    }
  }

  // LoRA K-extension tail (kh==1 only): BK=32, A from xap, B from btp
  if (kh == 1) {
    __syncthreads();
    *reinterpret_cast<uint4*>(&lds_b[0][brow * 72 + bq * 8]) = braw;
#pragma unroll
    for (int j = 0; j < 4; ++j)
      async16(xap + (size_t)(m0 + w * 64 + j * 16 + (lane >> 2)) * 32 + (lane & 3) * 8,
              lds_a + w * 2048 + j * 512 + lane * 8);
    __syncthreads();
    bf16x8 av[4], bv[4];
#pragma unroll
    for (int mi = 0; mi < 4; ++mi)
      av[mi] = ldfrag(lds_a + w * 2048 + (mi * 16 + (lane & 15)) * 32 + q * 8);
#pragma unroll
    for (int ni = 0; ni < 4; ++ni)
      bv[ni] = ldfrag(&lds_b[0][(ni * 16 + (lane & 15)) * 72 + q * 8]);
#pragma unroll
    for (int mi = 0; mi < 4; ++mi)
#pragma unroll
      for (int ni = 0; ni < 4; ++ni)
        acc[mi][ni] = __builtin_amdgcn_mfma_f32_16x16x32_bf16(av[mi], bv[ni],
                                                              acc[mi][ni], 0, 0, 0);
  }

  // epilogue: atomic add onto zero-initialized out
  const int rg = q * 4;
#pragma unroll
  for (int ni = 0; ni < 4; ++ni) {
    int col = o0 + ni * 16 + cl;
#pragma unroll
    for (int mi = 0; mi < 4; ++mi) {
      int row0 = m0 + w * 64 + mi * 16 + rg;
      float* op = out + (size_t)row0 * N_OUT + col;
#pragma unroll
      for (int i = 0; i < 4; ++i) atomicAdd(op + (size_t)i * N_OUT, acc[mi][ni][i]);
    }
  }
}

extern "C" void kernel_launch(void* const* d_in, const int* in_sizes, int n_in,
                              void* d_out, int out_size, void* d_ws, size_t ws_size,
                              hipStream_t stream) {
  const float* x = (const float*)d_in[0];
  const int* wi = (const int*)d_in[1];
  const float* sc = (const float*)d_in[2];
  const float* lA = (const float*)d_in[3];
  const float* lB = (const float*)d_in[4];
  const float* bias = (const float*)d_in[5];
  float* out = (float*)d_out;

  char* wsb = (char*)d_ws;
  ushort_t* xbf = (ushort_t*)wsb;                               // 4 MB
  ushort_t* xap = (ushort_t*)(wsb + (4u << 20));                // 32 KB
  ushort_t* btp = (ushort_t*)(wsb + (4u << 20) + (32u << 10));  // 704 KB

  hipMemsetAsync(out, 0, (size_t)out_size, stream);  // replaces bias-broadcast
  k_prep<<<811, 256, 0, stream>>>(x, lA, lB, xbf, xap, btp);
  k_main<<<688, 256, 0, stream>>>(xbf, wi, sc, xap, btp, bias, out);
}

// Round 13
// 335.576 us; speedup vs baseline: 1.1166x; 1.0175x over previous
//
#include <hip/hip_runtime.h>
#include <stdint.h>

typedef __bf16 bf16x8 __attribute__((ext_vector_type(8)));
typedef float f32x4 __attribute__((ext_vector_type(4)));
typedef unsigned short ushort_t;

#define N_OUT 11008
#define K_DIM 4096
#define M_DIM 512
#define BM 256
#define BN 64
#define BK 64
#define KHALF 2048
#define NT 32 /* KHALF / BK */
#define BSTRIDE (BN * 72)

__constant__ float c_nf4[16] = {
    -1.0f, -0.6961928009986877f, -0.5250730514526367f, -0.39491748809814453f,
    -0.28444138169288635f, -0.18477343022823334f, -0.09105003625154495f, 0.0f,
    0.07958029955625534f, 0.16093020141124725f, 0.24611230194568634f,
    0.33791524171829224f, 0.44070982933044434f, 0.5626170039176941f,
    0.7229568362236023f, 1.0f};

// round-half-up fp32 -> bf16, pack two into u32
__device__ __forceinline__ uint32_t pkbf(float lo, float hi) {
  uint32_t ul = __builtin_bit_cast(uint32_t, lo);
  uint32_t uh = __builtin_bit_cast(uint32_t, hi);
  return ((ul + 0x8000u) >> 16) | ((uh + 0x8000u) & 0xffff0000u);
}

__device__ __forceinline__ void async16(const void* g, void* l) {
  __builtin_amdgcn_global_load_lds(
      (const __attribute__((address_space(1))) void*)g,
      (__attribute__((address_space(3))) void*)l, 16, 0, 0);
}

__device__ __forceinline__ bf16x8 ldfrag(const ushort_t* p) {
  uint4 r = *reinterpret_cast<const uint4*>(p);
  return __builtin_bit_cast(bf16x8, r);
}

__device__ __forceinline__ uint32_t dq2(int a, int b, float s, const float2* lut) {
  float2 l = lut[a | (b << 4)];
  return pkbf(l.x * s, l.y * s);
}

// ====== fused prep: cvt+swizzle | x@A | B^T (811 fat blocks) — R12, passed ===
__global__ void k_prep(const float* __restrict__ x, const float* __restrict__ lA,
                       const float* __restrict__ lB,
                       ushort_t* __restrict__ xbf, ushort_t* __restrict__ xap,
                       ushort_t* __restrict__ btp) {
  const int b = blockIdx.x, t = threadIdx.x;
  if (b < 256) {
    // x fp32 -> bf16 with XOR chunk swizzle inside each 64-elem k-window
    int base = b * 1024 + t;
#pragma unroll
    for (int i = 0; i < 4; ++i) {
      int oc = base + i * 256;  // 16B output chunk id (8 bf16)
      int m = oc >> 9;          // 512 chunks per row
      int cr = oc & 511;
      int win = cr >> 3, cp = cr & 7;
      int c = cp ^ (m & 7);
      const float4* s4 = (const float4*)(x + (size_t)m * K_DIM + win * 64 + c * 8);
      float4 v0 = s4[0], v1 = s4[1];
      uint4 o;
      o.x = pkbf(v0.x, v0.y);
      o.y = pkbf(v0.z, v0.w);
      o.z = pkbf(v1.x, v1.y);
      o.w = pkbf(v1.z, v1.w);
      ((uint4*)xbf)[oc] = o;
    }
  } else if (b < 768) {
    // xa = 2*(x @ lora_A) for one row m, padded [512,32] bf16, coalesced
    __shared__ float red[256 * 17];
    int m = b - 256;
    f32x4 ac0 = 0.f, ac1 = 0.f, ac2 = 0.f, ac3 = 0.f;
#pragma unroll
    for (int i = 0; i < 16; ++i) {
      int k = i * 256 + t;
      float xk = x[(size_t)m * K_DIM + k];
      const f32x4* l4 = (const f32x4*)(lA + (size_t)k * 16);
      ac0 += xk * l4[0];
      ac1 += xk * l4[1];
      ac2 += xk * l4[2];
      ac3 += xk * l4[3];
    }
#pragma unroll
    for (int r = 0; r < 4; ++r) {
      red[t * 17 + r] = ac0[r];
      red[t * 17 + 4 + r] = ac1[r];
      red[t * 17 + 8 + r] = ac2[r];
      red[t * 17 + 12 + r] = ac3[r];
    }
    __syncthreads();
#pragma unroll
    for (int s = 128; s >= 16; s >>= 1) {
      if (t < s)
        for (int r = 0; r < 16; ++r) red[t * 17 + r] += red[(t + s) * 17 + r];
      __syncthreads();
    }
    if (t < 32) {
      float v = 0.f;
      if (t < 16) {
        for (int p = 0; p < 16; ++p) v += red[p * 17 + t];
        v *= 2.0f;  // SCALING
      }
      uint32_t u = __builtin_bit_cast(uint32_t, v);
      xap[(size_t)m * 32 + t] = (ushort_t)((u + 0x8000u) >> 16);
    }
  } else {
    // Bt = lora_B^T, padded [11008,32] bf16
    int o = (b - 768) * 256 + t;
    uint32_t p[8];
#pragma unroll
    for (int j = 0; j < 8; ++j)
      p[j] = pkbf(lB[(size_t)(2 * j) * N_OUT + o], lB[(size_t)(2 * j + 1) * N_OUT + o]);
    uint4* dst = reinterpret_cast<uint4*>(btp + (size_t)o * 32);
    dst[0] = make_uint4(p[0], p[1], p[2], p[3]);
    dst[1] = make_uint4(p[4], p[5], p[6], p[7]);
    dst[2] = make_uint4(0u, 0u, 0u, 0u);
    dst[3] = make_uint4(0u, 0u, 0u, 0u);
  }
}

// =============== main fused GEMM (split-K=2, atomic epilogue) ===============
// R12 structure (single __syncthreads/tile, lds_b dbuf, XCD swizzle) with the
// idx prefetch deepened 1 -> 2 tiles. Why: idx is consumed at dequant, which
// each wave reaches after only ~400cy of its own MFMA issue — shorter than
// the loaded-wi latency -> ~1 us/tile exposed wait (R7-R11 proved k_main
// <=106 us when idx is cheap). Consuming idx at dequant(kt+2) instead bounds
// the wait by the barrier(kt+1) vmcnt drain, a full tile (~8K cy) after
// issue >> latency -> stall vanishes. Implemented as a 2x-unrolled loop with
// NAMED biA/biB register buffers (no runtime-indexed arrays -> no scratch);
// __syncthreads semantics untouched (the pattern R2/R5 broke with raw
// barriers + sched_barrier is NOT repeated here).
__launch_bounds__(256, 3)
__global__ void k_main(const ushort_t* __restrict__ xbf, const int* __restrict__ wi,
                       const float* __restrict__ sc, const ushort_t* __restrict__ xap,
                       const ushort_t* __restrict__ btp,
                       const float* __restrict__ bias, float* __restrict__ out) {
  __shared__ __align__(16) ushort_t lds_a[BM * BK];     // 32 KB, [row][c'], swizzled
  __shared__ __align__(16) ushort_t lds_b[2][BSTRIDE];  // 2 x 9 KB, +8 pad, dbuf
  __shared__ float2 lutp[256];                          // pair LUT, 2 KB

  const int t = threadIdx.x;
  const int lane = t & 63;
  const int w = t >> 6;

  // XCD swizzle: 688 = 8 XCDs x 86 (bijective); 4 (m0,kh) siblings adjacent.
  const int n = blockIdx.x;
  const int wg = (n & 7) * 86 + (n >> 3);
  const int o0 = (wg >> 2) * BN;
  const int kh = (wg >> 1) & 1;
  const int m0 = (wg & 1) * BM;
  const int k0 = kh * KHALF;

  lutp[t] = make_float2(c_nf4[t & 15], c_nf4[t >> 4]);

  // B staging: thread -> (row=t>>2, 16 ints at (t&3)*16)
  const int brow = t >> 2, bq = t & 3;
  const int* gb0 = wi + (size_t)(o0 + brow) * K_DIM + k0 + bq * 16;
  const float* gs = sc + (size_t)(o0 + brow) * 64 + kh * 32;  // 1 scale/row/tile
  ushort_t* lb = &lds_b[0][brow * 72 + bq * 16];

  // A DMA: wave w stages its own rows [w*64, w*64+64); 8 instrs x 1KB
  const ushort_t* ga =
      xbf + (size_t)(m0 + w * 64 + (lane >> 3)) * K_DIM + k0 + (lane & 7) * 8;
  ushort_t* la_dst = lds_a + w * 4096 + lane * 8;

  // acc init: kh==1 carries the bias (out itself is zero-filled by memset)
  const int cl = lane & 15;
  f32x4 acc[4][4];
#pragma unroll
  for (int ni = 0; ni < 4; ++ni) {
    float b0 = (kh == 1) ? bias[o0 + ni * 16 + cl] : 0.f;
#pragma unroll
    for (int mi = 0; mi < 4; ++mi) acc[mi][ni] = (f32x4){b0, b0, b0, b0};
  }

  // prologue: 2-deep idx prefetch — biA holds even-tile idx, biB odd-tile
  int4 biA0 = ((const int4*)gb0)[0], biA1 = ((const int4*)gb0)[1];
  int4 biA2 = ((const int4*)gb0)[2], biA3 = ((const int4*)gb0)[3];
  float sA = gs[0];
  const int4* g1 = (const int4*)(gb0 + BK);
  int4 biB0 = g1[0], biB1 = g1[1], biB2 = g1[2], biB3 = g1[3];
  float sB = gs[1];

  const ushort_t* afb = lds_a + (w * 64 + (lane & 15)) * BK;
  const int q = lane >> 4;
  const ushort_t* bfb = &lds_b[0][(lane & 15) * 72 + q * 8];

  __syncthreads();  // lutp visible before first dequant

// one tile: dequant BI -> b[PB]; DMA(KT); sync; refill BI = idx(KT+2)
// (clamped, unconditional); MFMA from b[PB].
#define TILE(KT, PB, B0, B1, B2, B3, SS)                                        \
  {                                                                             \
    const int kt_ = (KT);                                                       \
    uint4 w0, w1;                                                               \
    w0.x = dq2(B0.x, B0.y, SS, lutp);                                           \
    w0.y = dq2(B0.z, B0.w, SS, lutp);                                           \
    w0.z = dq2(B1.x, B1.y, SS, lutp);                                           \
    w0.w = dq2(B1.z, B1.w, SS, lutp);                                           \
    w1.x = dq2(B2.x, B2.y, SS, lutp);                                           \
    w1.y = dq2(B2.z, B2.w, SS, lutp);                                           \
    w1.z = dq2(B3.x, B3.y, SS, lutp);                                           \
    w1.w = dq2(B3.z, B3.w, SS, lutp);                                           \
    ushort_t* lbk = lb + (PB)*BSTRIDE;                                          \
    *reinterpret_cast<uint4*>(lbk) = w0;                                        \
    *reinterpret_cast<uint4*>(lbk + 8) = w1;                                    \
    _Pragma("unroll") for (int j = 0; j < 8; ++j)                               \
        async16(ga + (size_t)j * 8 * K_DIM + kt_ * BK, la_dst + j * 512);       \
    __syncthreads(); /* drains DMA + publishes b[PB] */                         \
    {                                                                           \
      const int ksc = (kt_ + 2 < NT) ? kt_ + 2 : NT - 1; /* clamped refill */   \
      const int4* gbk = (const int4*)(gb0 + (size_t)ksc * BK);                  \
      B0 = gbk[0];                                                              \
      B1 = gbk[1];                                                              \
      B2 = gbk[2];                                                              \
      B3 = gbk[3];                                                              \
      SS = gs[ksc];                                                             \
    }                                                                           \
    const ushort_t* bfbk = bfb + (PB)*BSTRIDE;                                  \
    _Pragma("unroll") for (int kc = 0; kc < 2; ++kc) {                          \
      const int cpr = ((kc * 4 + q) ^ (lane & 7)) * 8;                          \
      bf16x8 av[4], bv[4];                                                      \
      _Pragma("unroll") for (int mi = 0; mi < 4; ++mi)                          \
          av[mi] = ldfrag(afb + mi * 16 * BK + cpr);                            \
      _Pragma("unroll") for (int ni = 0; ni < 4; ++ni)                          \
          bv[ni] = ldfrag(bfbk + ni * 16 * 72 + kc * 32);                       \
      _Pragma("unroll") for (int mi = 0; mi < 4; ++mi)                          \
          _Pragma("unroll") for (int ni = 0; ni < 4; ++ni)                      \
              acc[mi][ni] = __builtin_amdgcn_mfma_f32_16x16x32_bf16(            \
                  av[mi], bv[ni], acc[mi][ni], 0, 0, 0);                        \
    }                                                                           \
  }

#pragma unroll 1
  for (int kt2 = 0; kt2 < NT / 2; ++kt2) {
    TILE(2 * kt2, 0, biA0, biA1, biA2, biA3, sA)
    TILE(2 * kt2 + 1, 1, biB0, biB1, biB2, biB3, sB)
  }
#undef TILE

  // LoRA K-extension tail (kh==1 only): BK=32, A from xap, B from btp
  if (kh == 1) {
    uint4 braw = *reinterpret_cast<const uint4*>(btp + (size_t)(o0 + brow) * 32 + bq * 8);
    __syncthreads();
    *reinterpret_cast<uint4*>(&lds_b[0][brow * 72 + bq * 8]) = braw;
#pragma unroll
    for (int j = 0; j < 4; ++j)
      async16(xap + (size_t)(m0 + w * 64 + j * 16 + (lane >> 2)) * 32 + (lane & 3) * 8,
              lds_a + w * 2048 + j * 512 + lane * 8);
    __syncthreads();
    bf16x8 av[4], bv[4];
#pragma unroll
    for (int mi = 0; mi < 4; ++mi)
      av[mi] = ldfrag(lds_a + w * 2048 + (mi * 16 + (lane & 15)) * 32 + q * 8);
#pragma unroll
    for (int ni = 0; ni < 4; ++ni)
      bv[ni] = ldfrag(&lds_b[0][(ni * 16 + (lane & 15)) * 72 + q * 8]);
#pragma unroll
    for (int mi = 0; mi < 4; ++mi)
#pragma unroll
      for (int ni = 0; ni < 4; ++ni)
        acc[mi][ni] = __builtin_amdgcn_mfma_f32_16x16x32_bf16(av[mi], bv[ni],
                                                              acc[mi][ni], 0, 0, 0);
  }

  // epilogue: atomic add onto zero-initialized out
  const int rg = q * 4;
#pragma unroll
  for (int ni = 0; ni < 4; ++ni) {
    int col = o0 + ni * 16 + cl;
#pragma unroll
    for (int mi = 0; mi < 4; ++mi) {
      int row0 = m0 + w * 64 + mi * 16 + rg;
      float* op = out + (size_t)row0 * N_OUT + col;
#pragma unroll
      for (int i = 0; i < 4; ++i) atomicAdd(op + (size_t)i * N_OUT, acc[mi][ni][i]);
    }
  }
}

extern "C" void kernel_launch(void* const* d_in, const int* in_sizes, int n_in,
                              void* d_out, int out_size, void* d_ws, size_t ws_size,
                              hipStream_t stream) {
  const float* x = (const float*)d_in[0];
  const int* wi = (const int*)d_in[1];
  const float* sc = (const float*)d_in[2];
  const float* lA = (const float*)d_in[3];
  const float* lB = (const float*)d_in[4];
  const float* bias = (const float*)d_in[5];
  float* out = (float*)d_out;

  char* wsb = (char*)d_ws;
  ushort_t* xbf = (ushort_t*)wsb;                               // 4 MB
  ushort_t* xap = (ushort_t*)(wsb + (4u << 20));                // 32 KB
  ushort_t* btp = (ushort_t*)(wsb + (4u << 20) + (32u << 10));  // 704 KB

  hipMemsetAsync(out, 0, (size_t)out_size, stream);  // replaces bias-broadcast
  k_prep<<<811, 256, 0, stream>>>(x, lA, lB, xbf, xap, btp);
  k_main<<<688, 256, 0, stream>>>(xbf, wi, sc, xap, btp, bias, out);
}